// Round 14
// baseline (821.410 us; speedup 1.0000x reference)
//
#include <hip/hip_runtime.h>
#include <hip/hip_bf16.h>
#include <cstdint>
#include <cstddef>

#define BLK 256     // pack/zero/scatter/final block size
#define DG 12
#define GD 64                     // grid cells per dim
#define NCELL (GD * GD * GD)      // 262144 cells per side
static constexpr float X0_ = -8.0f, INVH_ = 4.0f, H_ = 0.25f;

static constexpr float EPS_ = 0.01f;
// exp(-d/sigma) = exp2(C2*d), C2 = -1/(sigma*ln2), sigma=2.5; C2SQ = C2^2
static constexpr float C2SQ_ = 0.333019070232236f;

typedef __attribute__((ext_vector_type(2))) float v2f;   // packed fp32 (VOP3P)
typedef __attribute__((ext_vector_type(8))) short v8s;   // 8 bf16 (MFMA A/B frag)
typedef __attribute__((ext_vector_type(4))) float v4f;   // MFMA C/D frag

__device__ __forceinline__ int cell_of(float x) {
    int c = (int)floorf((x - X0_) * INVH_);
    return c < 0 ? 0 : (c > GD - 1 ? GD - 1 : c);
}

// ---------------------------------------------------------------------------
// Kernel A: zero the cell-count arrays (2*NCELL ints).
// ---------------------------------------------------------------------------
__global__ __launch_bounds__(BLK) void pip_zero(int* __restrict__ cnt) {
    const int i = blockIdx.x * BLK + threadIdx.x;
    if (i < 2 * NCELL) cnt[i] = 0;
}

// ---------------------------------------------------------------------------
// Kernel B: pack RBF streams + fpk B-frags + init red + count grid cells.
//  pkps[side*P+pr] -> {x0,x1,y0,y1},{z0,z1,h0,h1}  h=C2SQ*|p|^2 (prescaled)
//  fpk[side][tile][lane] -> int4 B-frag of F=[s_x(12),1.0] bf16
//  cnt[side*NCELL+cell]++ for each g1_pos/g2_pos point (argmin grid build).
// ---------------------------------------------------------------------------
__global__ __launch_bounds__(BLK) void pip_pack(
    const float* __restrict__ g1_pos, const float* __restrict__ g2_pos,
    const float* __restrict__ s1_v,   const float* __restrict__ s1_x,
    const float* __restrict__ s2_v,   const float* __restrict__ s2_x,
    float4* __restrict__ pkps, int4* __restrict__ fpk, int* __restrict__ cnt,
    float* __restrict__ red, int N, int T, int L)
{
#pragma clang fp contract(off)
    const int P = T * 16;
    const int tid = blockIdx.x * BLK + threadIdx.x;

    if (tid < 26 * L) red[tid] = 0.f;   // init feature/norm accumulators

    if (tid < 2 * P) {                  // pkps: tid = side*P + pr
        const int side = tid / P;
        const int pr = tid - side * P;
        const float* src = side ? s2_v : s1_v;
        const int n0 = 2 * pr, n1 = 2 * pr + 1;
        float x0 = 1e9f, y0 = 1e9f, z0 = 1e9f, h0 = 1e18f;
        float x1 = 1e9f, y1 = 1e9f, z1 = 1e9f, h1 = 1e18f;
        if (n0 < N) {
            x0 = src[3 * n0]; y0 = src[3 * n0 + 1]; z0 = src[3 * n0 + 2];
            h0 = C2SQ_ * ((x0 * x0 + y0 * y0) + z0 * z0);
        }
        if (n1 < N) {
            x1 = src[3 * n1]; y1 = src[3 * n1 + 1]; z1 = src[3 * n1 + 2];
            h1 = C2SQ_ * ((x1 * x1 + y1 * y1) + z1 * z1);
        }
        pkps[(size_t)tid * 2 + 0] = make_float4(x0, x1, y0, y1);
        pkps[(size_t)tid * 2 + 1] = make_float4(z0, z1, h0, h1);
    } else if (tid < 2 * P + 128 * T) { // fpk B-fragments
        const int u = tid - 2 * P;
        const int side = u / (64 * T);
        const int r = u - side * 64 * T;
        const int t = r >> 6;
        const int ln = r & 63;
        const float* X = side ? s2_x : s1_x;
        const int nb = 32 * t + ((ln >> 4) << 3);
        const int feat = ln & 15;
        int w[4];
#pragma unroll
        for (int d = 0; d < 4; ++d) {
            const int n0 = nb + 2 * d, n1 = nb + 2 * d + 1;
            const float f0 = (n0 < N) ? (feat < 12 ? X[(size_t)n0 * DG + feat] : (feat == 12 ? 1.f : 0.f)) : 0.f;
            const float f1 = (n1 < N) ? (feat < 12 ? X[(size_t)n1 * DG + feat] : (feat == 12 ? 1.f : 0.f)) : 0.f;
            __hip_bfloat162 h = __float22bfloat162_rn(make_float2(f0, f1));
            __builtin_memcpy(&w[d], &h, 4);
        }
        fpk[((size_t)side * T + t) * 64 + ln] = make_int4(w[0], w[1], w[2], w[3]);
    } else if (tid < 2 * P + 128 * T + 2 * N) {  // grid cell counting
        const int u = tid - (2 * P + 128 * T);
        const int side = u / N;
        const int n = u - side * N;
        const float* src = side ? g2_pos : g1_pos;
        const float x = src[3 * n], y = src[3 * n + 1], z = src[3 * n + 2];
        const int c = (cell_of(x) * GD + cell_of(y)) * GD + cell_of(z);
        atomicAdd(&cnt[side * NCELL + c], 1);
    }
}

// ---------------------------------------------------------------------------
// Kernel C: exclusive scan of counts -> offsets; counts become cursors.
// Single block, 1024 threads; each owns a contiguous range of 2*NCELL/1024.
// ---------------------------------------------------------------------------
__global__ __launch_bounds__(1024) void pip_scan(
    int* __restrict__ cnt, int* __restrict__ off)
{
    __shared__ int lbase[1024];
    const int t = threadIdx.x;
    const int per = (2 * NCELL) / 1024;   // 512
    int s = 0;
    for (int i = 0; i < per; ++i) s += cnt[t * per + i];
    lbase[t] = s;
    __syncthreads();
    if (t == 0) {
        int acc = 0;
        for (int i = 0; i < 1024; ++i) { const int v = lbase[i]; lbase[i] = acc; acc += v; }
    }
    __syncthreads();
    int base = lbase[t];
    for (int i = 0; i < per; ++i) {
        const int idx = t * per + i;
        const int c = cnt[idx];
        off[idx] = base;
        cnt[idx] = base;      // cursor init; scatter bumps to end offset
        base += c;
    }
}

// ---------------------------------------------------------------------------
// Kernel D: scatter points into grid order. grid_pts[slot]={x,y,z,|p|^2/2},
// grid_id[slot]=n. Slots are globally disjoint (scan spans both sides).
// pn2h uses the exact reference arithmetic ((x*x+y*y)+z*z, no fma) * 0.5.
// ---------------------------------------------------------------------------
__global__ __launch_bounds__(BLK) void pip_scatter(
    const float* __restrict__ g1_pos, const float* __restrict__ g2_pos,
    int* __restrict__ cursor, float4* __restrict__ grid_pts,
    int* __restrict__ grid_id, int N)
{
#pragma clang fp contract(off)
    const int u = blockIdx.x * BLK + threadIdx.x;
    if (u >= 2 * N) return;
    const int side = u / N;
    const int n = u - side * N;
    const float* src = side ? g2_pos : g1_pos;
    const float x = src[3 * n], y = src[3 * n + 1], z = src[3 * n + 2];
    const float h = 0.5f * ((x * x + y * y) + z * z);
    const int c = (cell_of(x) * GD + cell_of(y)) * GD + cell_of(z);
    const int slot = atomicAdd(&cursor[side * NCELL + c], 1);
    grid_pts[slot] = make_float4(x, y, z, h);
    grid_id[slot] = n;
}

// ---------------------------------------------------------------------------
// Kernel E: exact nearest-neighbor via grid. One WAVE per (query,side).
// Expanding Chebyshev shells; every scanned point gets BOTH a true-d2 (for
// the stopping bound) and the bit-exact half-scale trick d2h key
// ((nqh+pn2h)-fma-dot — identical to the reference's fp32 formula ordering).
// Stop when ((r-1)*h)^2 > best_true + 1e-3 (trick-vs-true skew <= ~3e-5:
// scanned set provably contains the reference's trick-argmin). u64 key min
// = (d2h bits, index) lexicographic = first-index tiebreak.
// ---------------------------------------------------------------------------
__global__ __launch_bounds__(128) void pip_nn(
    const float* __restrict__ locs_l, const float* __restrict__ locs_r,
    const int* __restrict__ off, const int* __restrict__ ends,
    const float4* __restrict__ grid_pts, const int* __restrict__ grid_id,
    unsigned long long* __restrict__ keys, int L)
{
#pragma clang fp contract(off)
    const int lane = threadIdx.x & 63;
    const int wv = threadIdx.x >> 6;
    const int id = blockIdx.x * 2 + wv;        // [0, 2L)
    const int side = id / L;
    const int lq = id - side * L;

    const float* __restrict__ locs = side ? locs_r : locs_l;
    const float qx = locs[3 * lq + 0];
    const float qy = locs[3 * lq + 1];
    const float qz = locs[3 * lq + 2];
    const float nqh = 0.5f * ((qx * qx + qy * qy) + qz * qz);

    const int cx = cell_of(qx), cy = cell_of(qy), cz = cell_of(qz);
    const int cb = side * NCELL;

    float bt = 3.4e38f;                 // best true d2 (wave-global after reduce)
    unsigned long long bk = ~0ull;      // best (trick d2h bits << 32 | idx)

    for (int r = 0; r <= 2 * GD; ++r) {
        if (r >= 2) {
            const float bnd = (float)(r - 1) * H_;
            if (bnd * bnd > bt + 1e-3f) break;
        }
        const int xlo = max(cx - r, 0), xhi = min(cx + r, GD - 1);
        const int ylo = max(cy - r, 0), yhi = min(cy + r, GD - 1);
        const int zlo = max(cz - r, 0), zhi = min(cz + r, GD - 1);
        for (int a = xlo; a <= xhi; ++a) {
            const int da = abs(a - cx);
            for (int b = ylo; b <= yhi; ++b) {
                const int db = abs(b - cy);
                for (int c = zlo; c <= zhi; ++c) {
                    const int dc = abs(c - cz);
                    const int ch = max(da, max(db, dc));
                    if (ch != r) continue;            // shell r only
                    const int ci = cb + (a * GD + b) * GD + c;
                    const int st = off[ci], en = ends[ci];
                    for (int j = st + lane; j < en; j += 64) {
                        const float4 gp = grid_pts[j];
                        const float dx = qx - gp.x, dy = qy - gp.y, dz = qz - gp.z;
                        const float dt = fmaf(dx, dx, fmaf(dy, dy, dz * dz));
                        bt = fminf(bt, dt);
                        const float dot = fmaf(qz, gp.z, fmaf(qy, gp.y, qx * gp.x));
                        const float d2h = (nqh + gp.w) - dot;   // exact ref formula (half-scale)
                        const unsigned long long key =
                            ((unsigned long long)__float_as_uint(d2h) << 32) |
                            (unsigned long long)(unsigned)grid_id[j];
                        bk = key < bk ? key : bk;
                    }
                }
            }
        }
        // wave-reduce best_true so the stop bound is wave-global
        for (int m = 1; m < 64; m <<= 1) bt = fminf(bt, __shfl_xor(bt, m));
    }

    for (int m = 1; m < 64; m <<= 1) {
        const unsigned long long o = __shfl_xor(bk, m);
        bk = o < bk ? o : bk;
    }
    if (lane == 0) keys[(size_t)side * L + lq] = bk;
}

// ---------------------------------------------------------------------------
// Kernel F: RBF partial scans (argmin removed — handled by pip_nn).
// Block = 128 thr = 2 waves; one side (blockIdx.z), one chunk (blockIdx.y).
// Per dp-group: 2 vector loads, packed prescaled dot-form distances,
// w = exp2(-sqrt(t)), 1-inst v_perm bf16 truncation pack, 4 MFMAs/tile.
// Feature sums accumulate via device atomicAdd into red.
// ---------------------------------------------------------------------------
__global__ __launch_bounds__(128, 4) void pip_partial(
    const float* __restrict__ locs_l, const float* __restrict__ locs_r,
    const float4* __restrict__ pkps, const int4* __restrict__ fpk,
    float* __restrict__ red, int L, int T, int CT, int P)
{
#pragma clang fp contract(off)
    const int lane = threadIdx.x & 63;
    const int wv = threadIdx.x >> 6;
    const int side = blockIdx.z;
    const int qbase = blockIdx.x * 128 + wv * 64;

    const float* __restrict__ locs = side ? locs_r : locs_l;

    // fragment-role queries: q = qbase + 16*mt + (lane&15); prescaled consts
    float nq2[4], m2x[4], m2y[4], m2z[4];
#pragma unroll
    for (int mt = 0; mt < 4; ++mt) {
        const int qm = qbase + 16 * mt + (lane & 15);
        const float a = locs[3 * qm + 0];
        const float b = locs[3 * qm + 1];
        const float c = locs[3 * qm + 2];
        nq2[mt] = C2SQ_ * ((a * a + b * b) + c * c);
        const float s2 = -2.0f * C2SQ_;
        m2x[mt] = s2 * a; m2y[mt] = s2 * b; m2z[mt] = s2 * c;
    }

    v4f cC[4];
#pragma unroll
    for (int mt = 0; mt < 4; ++mt) cC[mt] = (v4f)0.f;

    const float4* __restrict__ pkpb = pkps + (size_t)side * P * 2;

    const int t0 = blockIdx.y * CT;
    const int t1 = (t0 + CT < T) ? (t0 + CT) : T;

    for (int tg = t0; tg < t1; ++tg) {
        const v8s b = ((const v8s*)fpk)[((size_t)side * T + tg) * 64 + lane];
        union AF { int i[4]; v8s s; };
        AF af[4];
        const int pg0 = tg * 16 + ((lane >> 4) << 2);   // this lane's 4 point-pairs

#pragma unroll
        for (int dp = 0; dp < 4; ++dp) {
            const float4 FXY = pkpb[(size_t)(pg0 + dp) * 2 + 0];
            const float4 FZH = pkpb[(size_t)(pg0 + dp) * 2 + 1];
            const v2f px = {FXY.x, FXY.y}, py = {FXY.z, FXY.w};
            const v2f pz = {FZH.x, FZH.y}, ph = {FZH.z, FZH.w};
#pragma unroll
            for (int mt = 0; mt < 4; ++mt) {
                const v2f mx = {m2x[mt], m2x[mt]};
                const v2f my = {m2y[mt], m2y[mt]};
                const v2f mz = {m2z[mt], m2z[mt]};
                const v2f s  = nq2[mt] + ph;
                v2f t = __builtin_elementwise_fma(mz, pz,
                          __builtin_elementwise_fma(my, py,
                            __builtin_elementwise_fma(mx, px, s)));
                t = __builtin_elementwise_max(t, (v2f)0.f);   // cancellation guard
                const float w0 = __builtin_amdgcn_exp2f(-__builtin_amdgcn_sqrtf(t.x));
                const float w1 = __builtin_amdgcn_exp2f(-__builtin_amdgcn_sqrtf(t.y));
                af[mt].i[dp] = (int)__builtin_amdgcn_perm(
                    __float_as_uint(w1), __float_as_uint(w0), 0x07060302u);
            }
        }

#pragma unroll
        for (int mt = 0; mt < 4; ++mt)
            cC[mt] = __builtin_amdgcn_mfma_f32_16x16x32_bf16(af[mt].s, b, cC[mt], 0, 0, 0);
    }

    const int feat = lane & 15;
    if (feat < 13) {
        const int slot = side * 13 + feat;
        // C/D layout: col(=feat)=lane&15, row(=q within 16-tile)=(lane>>4)*4+reg
#pragma unroll
        for (int mt = 0; mt < 4; ++mt)
#pragma unroll
            for (int r = 0; r < 4; ++r) {
                const int q = qbase + 16 * mt + ((lane >> 4) << 2) + r;
                atomicAdd(&red[(size_t)slot * L + q], cC[mt][r]);
            }
    }
}

__device__ __forceinline__ float tanh_pos(float x) {
    const float t = __expf(-2.f * x);
    return (1.f - t) / (1.f + t);
}

// ---------------------------------------------------------------------------
// Kernel G: gather nearest-node feats + 50->50->1 MLP. Thread = one query l.
// ---------------------------------------------------------------------------
__global__ __launch_bounds__(BLK) void pip_final(
    const float* __restrict__ red, const unsigned long long* __restrict__ keys,
    const float* __restrict__ g1_x, const float* __restrict__ g2_x,
    const float* __restrict__ W1, const float* __restrict__ b1,
    const float* __restrict__ W2, const float* __restrict__ b2,
    float* __restrict__ out, int L)
{
#pragma clang fp contract(off)
    const int l = blockIdx.x * BLK + threadIdx.x;
    if (l >= L) return;

    const unsigned idxL = (unsigned)(keys[l] & 0xffffffffull);
    const unsigned idxR = (unsigned)(keys[(size_t)L + l] & 0xffffffffull);
    const float normL = red[(size_t)12 * L + (size_t)l] + EPS_;
    const float normR = red[(size_t)25 * L + (size_t)l] + EPS_;

    float x[50];
    {
        const float4* f = (const float4*)(g1_x + (size_t)idxL * DG);
        const float4 f0 = f[0], f1 = f[1], f2 = f[2];
        x[0] = f0.x; x[1] = f0.y; x[2]  = f0.z; x[3]  = f0.w;
        x[4] = f1.x; x[5] = f1.y; x[6]  = f1.z; x[7]  = f1.w;
        x[8] = f2.x; x[9] = f2.y; x[10] = f2.z; x[11] = f2.w;
    }
#pragma unroll
    for (int k = 0; k < DG; ++k) x[12 + k] = red[(size_t)k * L + (size_t)l] / normL;
    x[24] = tanh_pos(normL);
    {
        const float4* f = (const float4*)(g2_x + (size_t)idxR * DG);
        const float4 f0 = f[0], f1 = f[1], f2 = f[2];
        x[25] = f0.x; x[26] = f0.y; x[27] = f0.z; x[28] = f0.w;
        x[29] = f1.x; x[30] = f1.y; x[31] = f1.z; x[32] = f1.w;
        x[33] = f2.x; x[34] = f2.y; x[35] = f2.z; x[36] = f2.w;
    }
#pragma unroll
    for (int k = 0; k < DG; ++k) x[37 + k] = red[(size_t)(13 + k) * L + (size_t)l] / normR;
    x[49] = tanh_pos(normR);

    float h[50];
#pragma unroll
    for (int j = 0; j < 50; ++j) h[j] = b1[j];
#pragma unroll
    for (int k = 0; k < 50; ++k) {
        const float xk = x[k];
#pragma unroll
        for (int j = 0; j < 50; ++j) h[j] = fmaf(xk, W1[k * 50 + j], h[j]);
    }
    float o = b2[0];
#pragma unroll
    for (int j = 0; j < 50; ++j) o = fmaf(fmaxf(h[j], 0.f), W2[j], o);
    out[l] = o;
}

// ---------------------------------------------------------------------------
extern "C" void kernel_launch(void* const* d_in, const int* in_sizes, int n_in,
                              void* d_out, int out_size, void* d_ws, size_t ws_size,
                              hipStream_t stream) {
    const float* locs_l = (const float*)d_in[0];
    const float* locs_r = (const float*)d_in[1];
    const float* g1_pos = (const float*)d_in[2];
    const float* g1_x   = (const float*)d_in[3];
    const float* g2_pos = (const float*)d_in[4];
    const float* g2_x   = (const float*)d_in[5];
    const float* s1_v   = (const float*)d_in[6];
    const float* s1_x   = (const float*)d_in[7];
    const float* s2_v   = (const float*)d_in[8];
    const float* s2_x   = (const float*)d_in[9];
    const float* W1     = (const float*)d_in[10];
    const float* b1     = (const float*)d_in[11];
    const float* W2     = (const float*)d_in[12];
    const float* b2     = (const float*)d_in[13];
    float* out = (float*)d_out;
    float* ws  = (float*)d_ws;

    const int L = in_sizes[0] / 3;   // 4096
    const int N = in_sizes[2] / 3;   // 40000
    const int T = (N + 31) / 32;     // 32-point tiles (1250, exact)
    const int P = T * 16;            // point pairs

    // ws layout (floats):
    //  [pkps: 256T][fpk: 512T][red: 26L][keys: 2L u64]
    //  [cnt/cursor/end: 2*NCELL int][off: 2*NCELL int][grid_pts: 8N][grid_id: 2N]
    const size_t o_fpk  = (size_t)256 * T;
    const size_t o_red  = (size_t)768 * T;
    const size_t o_keys = o_red + (size_t)26 * L;
    const size_t o_cnt  = o_keys + (size_t)4 * L;
    const size_t o_off  = o_cnt + (size_t)2 * NCELL;
    const size_t o_gpts = o_off + (size_t)2 * NCELL;
    const size_t o_gid  = o_gpts + (size_t)8 * N;

    float4* pkps = (float4*)ws;
    int4*   fpk  = (int4*)(ws + o_fpk);
    float*  red  = ws + o_red;
    unsigned long long* keys = (unsigned long long*)(ws + o_keys);
    int*    cnt  = (int*)(ws + o_cnt);
    int*    off  = (int*)(ws + o_off);
    float4* gpts = (float4*)(ws + o_gpts);
    int*    gid  = (int*)(ws + o_gid);

    const int CT = 40;                       // tiles per chunk
    const int SC = (T + CT - 1) / CT;        // 32 chunks -> grid 32 x 32 x 2

    pip_zero<<<dim3((2 * NCELL + BLK - 1) / BLK), dim3(BLK), 0, stream>>>(cnt);

    const int ptasks = 2 * P + 128 * T + 2 * N;
    pip_pack<<<dim3((ptasks + BLK - 1) / BLK), dim3(BLK), 0, stream>>>(
        g1_pos, g2_pos, s1_v, s1_x, s2_v, s2_x, pkps, fpk, cnt, red, N, T, L);

    pip_scan<<<dim3(1), dim3(1024), 0, stream>>>(cnt, off);

    pip_scatter<<<dim3((2 * N + BLK - 1) / BLK), dim3(BLK), 0, stream>>>(
        g1_pos, g2_pos, cnt, gpts, gid, N);

    pip_nn<<<dim3(L), dim3(128), 0, stream>>>(
        locs_l, locs_r, off, cnt, gpts, gid, keys, L);

    pip_partial<<<dim3(L / 128, SC, 2), dim3(128), 0, stream>>>(
        locs_l, locs_r, pkps, fpk, red, L, T, CT, P);

    pip_final<<<dim3((L + BLK - 1) / BLK), dim3(BLK), 0, stream>>>(
        red, keys, g1_x, g2_x, W1, b1, W2, b2, out, L);
}

// Round 15
// 478.799 us; speedup vs baseline: 1.7156x; 1.7156x over previous
//
#include <hip/hip_runtime.h>
#include <hip/hip_bf16.h>
#include <cstdint>
#include <cstddef>

#define BLK 256     // pack/zero/scatter/final block size
#define DG 12
#define GD 32                     // grid cells per dim
#define NCELL (GD * GD * GD)      // 32768 cells per side
static constexpr float X0_ = -8.0f, INVH_ = 2.0f, H_ = 0.5f;

static constexpr float EPS_ = 0.01f;
// exp(-d/sigma) = exp2(C2*d), C2 = -1/(sigma*ln2), sigma=2.5; C2SQ = C2^2
static constexpr float C2SQ_ = 0.333019070232236f;

typedef __attribute__((ext_vector_type(2))) float v2f;   // packed fp32 (VOP3P)
typedef __attribute__((ext_vector_type(8))) short v8s;   // 8 bf16 (MFMA A/B frag)
typedef __attribute__((ext_vector_type(4))) float v4f;   // MFMA C/D frag

__device__ __forceinline__ int cell_of(float x) {
    int c = (int)floorf((x - X0_) * INVH_);
    return c < 0 ? 0 : (c > GD - 1 ? GD - 1 : c);
}

// ---------------------------------------------------------------------------
// Kernel A: zero the cell-count arrays (2*NCELL ints).
// ---------------------------------------------------------------------------
__global__ __launch_bounds__(BLK) void pip_zero(int* __restrict__ cnt) {
    const int i = blockIdx.x * BLK + threadIdx.x;
    if (i < 2 * NCELL) cnt[i] = 0;
}

// ---------------------------------------------------------------------------
// Kernel B: pack RBF streams + fpk B-frags + init red + count grid cells.
//  pkps[side*P+pr] -> {x0,x1,y0,y1},{z0,z1,h0,h1}  h=C2SQ*|p|^2 (prescaled)
//  fpk[side][tile][lane] -> int4 B-frag of F=[s_x(12),1.0] bf16
//  cnt[side*NCELL+cell]++ for each g1_pos/g2_pos point (argmin grid build).
// ---------------------------------------------------------------------------
__global__ __launch_bounds__(BLK) void pip_pack(
    const float* __restrict__ g1_pos, const float* __restrict__ g2_pos,
    const float* __restrict__ s1_v,   const float* __restrict__ s1_x,
    const float* __restrict__ s2_v,   const float* __restrict__ s2_x,
    float4* __restrict__ pkps, int4* __restrict__ fpk, int* __restrict__ cnt,
    float* __restrict__ red, int N, int T, int L)
{
#pragma clang fp contract(off)
    const int P = T * 16;
    const int tid = blockIdx.x * BLK + threadIdx.x;

    if (tid < 26 * L) red[tid] = 0.f;   // init feature/norm accumulators

    if (tid < 2 * P) {                  // pkps: tid = side*P + pr
        const int side = tid / P;
        const int pr = tid - side * P;
        const float* src = side ? s2_v : s1_v;
        const int n0 = 2 * pr, n1 = 2 * pr + 1;
        float x0 = 1e9f, y0 = 1e9f, z0 = 1e9f, h0 = 1e18f;
        float x1 = 1e9f, y1 = 1e9f, z1 = 1e9f, h1 = 1e18f;
        if (n0 < N) {
            x0 = src[3 * n0]; y0 = src[3 * n0 + 1]; z0 = src[3 * n0 + 2];
            h0 = C2SQ_ * ((x0 * x0 + y0 * y0) + z0 * z0);
        }
        if (n1 < N) {
            x1 = src[3 * n1]; y1 = src[3 * n1 + 1]; z1 = src[3 * n1 + 2];
            h1 = C2SQ_ * ((x1 * x1 + y1 * y1) + z1 * z1);
        }
        pkps[(size_t)tid * 2 + 0] = make_float4(x0, x1, y0, y1);
        pkps[(size_t)tid * 2 + 1] = make_float4(z0, z1, h0, h1);
    } else if (tid < 2 * P + 128 * T) { // fpk B-fragments
        const int u = tid - 2 * P;
        const int side = u / (64 * T);
        const int r = u - side * 64 * T;
        const int t = r >> 6;
        const int ln = r & 63;
        const float* X = side ? s2_x : s1_x;
        const int nb = 32 * t + ((ln >> 4) << 3);
        const int feat = ln & 15;
        int w[4];
#pragma unroll
        for (int d = 0; d < 4; ++d) {
            const int n0 = nb + 2 * d, n1 = nb + 2 * d + 1;
            const float f0 = (n0 < N) ? (feat < 12 ? X[(size_t)n0 * DG + feat] : (feat == 12 ? 1.f : 0.f)) : 0.f;
            const float f1 = (n1 < N) ? (feat < 12 ? X[(size_t)n1 * DG + feat] : (feat == 12 ? 1.f : 0.f)) : 0.f;
            __hip_bfloat162 h = __float22bfloat162_rn(make_float2(f0, f1));
            __builtin_memcpy(&w[d], &h, 4);
        }
        fpk[((size_t)side * T + t) * 64 + ln] = make_int4(w[0], w[1], w[2], w[3]);
    } else if (tid < 2 * P + 128 * T + 2 * N) {  // grid cell counting
        const int u = tid - (2 * P + 128 * T);
        const int side = u / N;
        const int n = u - side * N;
        const float* src = side ? g2_pos : g1_pos;
        const float x = src[3 * n], y = src[3 * n + 1], z = src[3 * n + 2];
        const int c = (cell_of(x) * GD + cell_of(y)) * GD + cell_of(z);
        atomicAdd(&cnt[side * NCELL + c], 1);
    }
}

// ---------------------------------------------------------------------------
// Kernel C: exclusive scan of counts -> offsets; counts become cursors.
// 1024 threads; per-thread 64-cell block sum; Hillis-Steele tree scan in LDS.
// ---------------------------------------------------------------------------
__global__ __launch_bounds__(1024) void pip_scan(
    int* __restrict__ cnt, int* __restrict__ off)
{
    __shared__ int lds[1024];
    const int t = threadIdx.x;
    const int per = (2 * NCELL) / 1024;   // 64
    int s = 0;
#pragma unroll 8
    for (int i = 0; i < per; ++i) s += cnt[t * per + i];
    lds[t] = s;
    __syncthreads();
    for (int o = 1; o < 1024; o <<= 1) {
        const int v = (t >= o) ? lds[t - o] : 0;
        __syncthreads();
        lds[t] += v;
        __syncthreads();
    }
    int base = lds[t] - s;   // exclusive prefix of this thread's block
    for (int i = 0; i < per; ++i) {
        const int idx = t * per + i;
        const int c = cnt[idx];
        off[idx] = base;
        cnt[idx] = base;      // cursor init; scatter bumps to end offset
        base += c;
    }
}

// ---------------------------------------------------------------------------
// Kernel D: scatter points into grid order. grid_pts[slot]={x,y,z,|p|^2/2},
// grid_id[slot]=n. Slots are globally disjoint (scan spans both sides).
// pn2h uses the exact reference arithmetic ((x*x+y*y)+z*z, no fma) * 0.5.
// ---------------------------------------------------------------------------
__global__ __launch_bounds__(BLK) void pip_scatter(
    const float* __restrict__ g1_pos, const float* __restrict__ g2_pos,
    int* __restrict__ cursor, float4* __restrict__ grid_pts,
    int* __restrict__ grid_id, int N)
{
#pragma clang fp contract(off)
    const int u = blockIdx.x * BLK + threadIdx.x;
    if (u >= 2 * N) return;
    const int side = u / N;
    const int n = u - side * N;
    const float* src = side ? g2_pos : g1_pos;
    const float x = src[3 * n], y = src[3 * n + 1], z = src[3 * n + 2];
    const float h = 0.5f * ((x * x + y * y) + z * z);
    const int c = (cell_of(x) * GD + cell_of(y)) * GD + cell_of(z);
    const int slot = atomicAdd(&cursor[side * NCELL + c], 1);
    grid_pts[slot] = make_float4(x, y, z, h);
    grid_id[slot] = n;
}

// ---------------------------------------------------------------------------
// Kernel E: exact NN via grid, LANE-PARALLEL cell visits. One wave per
// (query,side). Cube radius doubles R=1,2,4..GD; each round distributes the
// (2R+1)^3 cells across the 64 lanes: off/ends are per-lane parallel loads
// (R14's wave-serial cell walk was the 306 us tail — latency now overlapped
// 64-wide), each lane scans its own cell's points. Rescans are harmless
// (min idempotent). Every point gets true-d2 (stop bound) AND the bit-exact
// half-scale trick key ((nqh+pn2h)-fma-dot = reference fp32 formula).
// Stop when (R*h)^2 > best_true + 1e-3 (trick-vs-true skew <= ~3e-5).
// R=GD scans the full grid -> unconditional correctness.
// ---------------------------------------------------------------------------
__global__ __launch_bounds__(64) void pip_nn(
    const float* __restrict__ locs_l, const float* __restrict__ locs_r,
    const int* __restrict__ off, const int* __restrict__ ends,
    const float4* __restrict__ grid_pts, const int* __restrict__ grid_id,
    unsigned long long* __restrict__ keys, int L)
{
#pragma clang fp contract(off)
    const int lane = threadIdx.x;
    const int id = blockIdx.x;                 // [0, 2L)
    const int side = id / L;
    const int lq = id - side * L;

    const float* __restrict__ locs = side ? locs_r : locs_l;
    const float qx = locs[3 * lq + 0];
    const float qy = locs[3 * lq + 1];
    const float qz = locs[3 * lq + 2];
    const float nqh = 0.5f * ((qx * qx + qy * qy) + qz * qz);

    const int cx = cell_of(qx), cy = cell_of(qy), cz = cell_of(qz);
    const int cb = side * NCELL;

    float bt = 3.4e38f;                 // best true d2 (per-lane until reduce)
    unsigned long long bk = ~0ull;      // best (trick d2h bits << 32 | idx)

    for (int R = 1; R <= GD; R <<= 1) {
        const int s = 2 * R + 1;
        const int ss = s * s;
        const int cube = ss * s;
        for (int base = 0; base < cube; base += 64) {
            const int idx = base + lane;
            int st = 0, en = 0;
            if (idx < cube) {
                const int a = idx / ss;
                const int rem = idx - a * ss;
                const int b = rem / s;
                const int c = rem - b * s;
                const int ca = cx + a - R, cbq = cy + b - R, cc = cz + c - R;
                if (ca >= 0 && ca < GD && cbq >= 0 && cbq < GD && cc >= 0 && cc < GD) {
                    const int ci = cb + (ca * GD + cbq) * GD + cc;
                    st = off[ci];
                    en = ends[ci];
                }
            }
            for (int j = st; j < en; ++j) {
                const float4 gp = grid_pts[j];
                const float dx = qx - gp.x, dy = qy - gp.y, dz = qz - gp.z;
                const float dt = fmaf(dx, dx, fmaf(dy, dy, dz * dz));
                bt = fminf(bt, dt);
                const float dot = fmaf(qz, gp.z, fmaf(qy, gp.y, qx * gp.x));
                const float d2h = (nqh + gp.w) - dot;   // exact ref formula (half-scale)
                const unsigned long long key =
                    ((unsigned long long)__float_as_uint(d2h) << 32) |
                    (unsigned long long)(unsigned)grid_id[j];
                bk = key < bk ? key : bk;
            }
        }
        // wave-reduce best_true; check stop bound
        for (int m = 1; m < 64; m <<= 1) bt = fminf(bt, __shfl_xor(bt, m));
        const float bnd = (float)R * H_;
        if (bnd * bnd > bt + 1e-3f) break;
    }

    for (int m = 1; m < 64; m <<= 1) {
        const unsigned long long o = __shfl_xor(bk, m);
        bk = o < bk ? o : bk;
    }
    if (lane == 0) keys[(size_t)side * L + lq] = bk;
}

// ---------------------------------------------------------------------------
// Kernel F: RBF partial scans (argmin handled by pip_nn).
// Block = 128 thr = 2 waves; one side (blockIdx.z), one chunk (blockIdx.y).
// Per dp-group: 2 vector loads, packed prescaled dot-form distances,
// w = exp2(-sqrt(t)), 1-inst v_perm bf16 truncation pack, 4 MFMAs/tile.
// Feature sums accumulate via device atomicAdd into red.
// ---------------------------------------------------------------------------
__global__ __launch_bounds__(128, 4) void pip_partial(
    const float* __restrict__ locs_l, const float* __restrict__ locs_r,
    const float4* __restrict__ pkps, const int4* __restrict__ fpk,
    float* __restrict__ red, int L, int T, int CT, int P)
{
#pragma clang fp contract(off)
    const int lane = threadIdx.x & 63;
    const int wv = threadIdx.x >> 6;
    const int side = blockIdx.z;
    const int qbase = blockIdx.x * 128 + wv * 64;

    const float* __restrict__ locs = side ? locs_r : locs_l;

    // fragment-role queries: q = qbase + 16*mt + (lane&15); prescaled consts
    float nq2[4], m2x[4], m2y[4], m2z[4];
#pragma unroll
    for (int mt = 0; mt < 4; ++mt) {
        const int qm = qbase + 16 * mt + (lane & 15);
        const float a = locs[3 * qm + 0];
        const float b = locs[3 * qm + 1];
        const float c = locs[3 * qm + 2];
        nq2[mt] = C2SQ_ * ((a * a + b * b) + c * c);
        const float s2 = -2.0f * C2SQ_;
        m2x[mt] = s2 * a; m2y[mt] = s2 * b; m2z[mt] = s2 * c;
    }

    v4f cC[4];
#pragma unroll
    for (int mt = 0; mt < 4; ++mt) cC[mt] = (v4f)0.f;

    const float4* __restrict__ pkpb = pkps + (size_t)side * P * 2;

    const int t0 = blockIdx.y * CT;
    const int t1 = (t0 + CT < T) ? (t0 + CT) : T;

    for (int tg = t0; tg < t1; ++tg) {
        const v8s b = ((const v8s*)fpk)[((size_t)side * T + tg) * 64 + lane];
        union AF { int i[4]; v8s s; };
        AF af[4];
        const int pg0 = tg * 16 + ((lane >> 4) << 2);   // this lane's 4 point-pairs

#pragma unroll
        for (int dp = 0; dp < 4; ++dp) {
            const float4 FXY = pkpb[(size_t)(pg0 + dp) * 2 + 0];
            const float4 FZH = pkpb[(size_t)(pg0 + dp) * 2 + 1];
            const v2f px = {FXY.x, FXY.y}, py = {FXY.z, FXY.w};
            const v2f pz = {FZH.x, FZH.y}, ph = {FZH.z, FZH.w};
#pragma unroll
            for (int mt = 0; mt < 4; ++mt) {
                const v2f mx = {m2x[mt], m2x[mt]};
                const v2f my = {m2y[mt], m2y[mt]};
                const v2f mz = {m2z[mt], m2z[mt]};
                const v2f s  = nq2[mt] + ph;
                v2f t = __builtin_elementwise_fma(mz, pz,
                          __builtin_elementwise_fma(my, py,
                            __builtin_elementwise_fma(mx, px, s)));
                t = __builtin_elementwise_max(t, (v2f)0.f);   // cancellation guard
                const float w0 = __builtin_amdgcn_exp2f(-__builtin_amdgcn_sqrtf(t.x));
                const float w1 = __builtin_amdgcn_exp2f(-__builtin_amdgcn_sqrtf(t.y));
                af[mt].i[dp] = (int)__builtin_amdgcn_perm(
                    __float_as_uint(w1), __float_as_uint(w0), 0x07060302u);
            }
        }

#pragma unroll
        for (int mt = 0; mt < 4; ++mt)
            cC[mt] = __builtin_amdgcn_mfma_f32_16x16x32_bf16(af[mt].s, b, cC[mt], 0, 0, 0);
    }

    const int feat = lane & 15;
    if (feat < 13) {
        const int slot = side * 13 + feat;
        // C/D layout: col(=feat)=lane&15, row(=q within 16-tile)=(lane>>4)*4+reg
#pragma unroll
        for (int mt = 0; mt < 4; ++mt)
#pragma unroll
            for (int r = 0; r < 4; ++r) {
                const int q = qbase + 16 * mt + ((lane >> 4) << 2) + r;
                atomicAdd(&red[(size_t)slot * L + q], cC[mt][r]);
            }
    }
}

__device__ __forceinline__ float tanh_pos(float x) {
    const float t = __expf(-2.f * x);
    return (1.f - t) / (1.f + t);
}

// ---------------------------------------------------------------------------
// Kernel G: gather nearest-node feats + 50->50->1 MLP. Thread = one query l.
// ---------------------------------------------------------------------------
__global__ __launch_bounds__(BLK) void pip_final(
    const float* __restrict__ red, const unsigned long long* __restrict__ keys,
    const float* __restrict__ g1_x, const float* __restrict__ g2_x,
    const float* __restrict__ W1, const float* __restrict__ b1,
    const float* __restrict__ W2, const float* __restrict__ b2,
    float* __restrict__ out, int L)
{
#pragma clang fp contract(off)
    const int l = blockIdx.x * BLK + threadIdx.x;
    if (l >= L) return;

    const unsigned idxL = (unsigned)(keys[l] & 0xffffffffull);
    const unsigned idxR = (unsigned)(keys[(size_t)L + l] & 0xffffffffull);
    const float normL = red[(size_t)12 * L + (size_t)l] + EPS_;
    const float normR = red[(size_t)25 * L + (size_t)l] + EPS_;

    float x[50];
    {
        const float4* f = (const float4*)(g1_x + (size_t)idxL * DG);
        const float4 f0 = f[0], f1 = f[1], f2 = f[2];
        x[0] = f0.x; x[1] = f0.y; x[2]  = f0.z; x[3]  = f0.w;
        x[4] = f1.x; x[5] = f1.y; x[6]  = f1.z; x[7]  = f1.w;
        x[8] = f2.x; x[9] = f2.y; x[10] = f2.z; x[11] = f2.w;
    }
#pragma unroll
    for (int k = 0; k < DG; ++k) x[12 + k] = red[(size_t)k * L + (size_t)l] / normL;
    x[24] = tanh_pos(normL);
    {
        const float4* f = (const float4*)(g2_x + (size_t)idxR * DG);
        const float4 f0 = f[0], f1 = f[1], f2 = f[2];
        x[25] = f0.x; x[26] = f0.y; x[27] = f0.z; x[28] = f0.w;
        x[29] = f1.x; x[30] = f1.y; x[31] = f1.z; x[32] = f1.w;
        x[33] = f2.x; x[34] = f2.y; x[35] = f2.z; x[36] = f2.w;
    }
#pragma unroll
    for (int k = 0; k < DG; ++k) x[37 + k] = red[(size_t)(13 + k) * L + (size_t)l] / normR;
    x[49] = tanh_pos(normR);

    float h[50];
#pragma unroll
    for (int j = 0; j < 50; ++j) h[j] = b1[j];
#pragma unroll
    for (int k = 0; k < 50; ++k) {
        const float xk = x[k];
#pragma unroll
        for (int j = 0; j < 50; ++j) h[j] = fmaf(xk, W1[k * 50 + j], h[j]);
    }
    float o = b2[0];
#pragma unroll
    for (int j = 0; j < 50; ++j) o = fmaf(fmaxf(h[j], 0.f), W2[j], o);
    out[l] = o;
}

// ---------------------------------------------------------------------------
extern "C" void kernel_launch(void* const* d_in, const int* in_sizes, int n_in,
                              void* d_out, int out_size, void* d_ws, size_t ws_size,
                              hipStream_t stream) {
    const float* locs_l = (const float*)d_in[0];
    const float* locs_r = (const float*)d_in[1];
    const float* g1_pos = (const float*)d_in[2];
    const float* g1_x   = (const float*)d_in[3];
    const float* g2_pos = (const float*)d_in[4];
    const float* g2_x   = (const float*)d_in[5];
    const float* s1_v   = (const float*)d_in[6];
    const float* s1_x   = (const float*)d_in[7];
    const float* s2_v   = (const float*)d_in[8];
    const float* s2_x   = (const float*)d_in[9];
    const float* W1     = (const float*)d_in[10];
    const float* b1     = (const float*)d_in[11];
    const float* W2     = (const float*)d_in[12];
    const float* b2     = (const float*)d_in[13];
    float* out = (float*)d_out;
    float* ws  = (float*)d_ws;

    const int L = in_sizes[0] / 3;   // 4096
    const int N = in_sizes[2] / 3;   // 40000
    const int T = (N + 31) / 32;     // 32-point tiles (1250, exact)
    const int P = T * 16;            // point pairs

    // ws layout (floats):
    //  [pkps: 256T][fpk: 512T][red: 26L][keys: 2L u64]
    //  [cnt/cursor/end: 2*NCELL int][off: 2*NCELL int][grid_pts: 8N][grid_id: 2N]
    const size_t o_fpk  = (size_t)256 * T;
    const size_t o_red  = (size_t)768 * T;
    const size_t o_keys = o_red + (size_t)26 * L;
    const size_t o_cnt  = o_keys + (size_t)4 * L;
    const size_t o_off  = o_cnt + (size_t)2 * NCELL;
    const size_t o_gpts = o_off + (size_t)2 * NCELL;
    const size_t o_gid  = o_gpts + (size_t)8 * N;

    float4* pkps = (float4*)ws;
    int4*   fpk  = (int4*)(ws + o_fpk);
    float*  red  = ws + o_red;
    unsigned long long* keys = (unsigned long long*)(ws + o_keys);
    int*    cnt  = (int*)(ws + o_cnt);
    int*    off  = (int*)(ws + o_off);
    float4* gpts = (float4*)(ws + o_gpts);
    int*    gid  = (int*)(ws + o_gid);

    const int CT = 40;                       // tiles per chunk
    const int SC = (T + CT - 1) / CT;        // 32 chunks -> grid 32 x 32 x 2

    pip_zero<<<dim3((2 * NCELL + BLK - 1) / BLK), dim3(BLK), 0, stream>>>(cnt);

    const int ptasks = 2 * P + 128 * T + 2 * N;
    pip_pack<<<dim3((ptasks + BLK - 1) / BLK), dim3(BLK), 0, stream>>>(
        g1_pos, g2_pos, s1_v, s1_x, s2_v, s2_x, pkps, fpk, cnt, red, N, T, L);

    pip_scan<<<dim3(1), dim3(1024), 0, stream>>>(cnt, off);

    pip_scatter<<<dim3((2 * N + BLK - 1) / BLK), dim3(BLK), 0, stream>>>(
        g1_pos, g2_pos, cnt, gpts, gid, N);

    pip_nn<<<dim3(2 * L), dim3(64), 0, stream>>>(
        locs_l, locs_r, off, cnt, gpts, gid, keys, L);

    pip_partial<<<dim3(L / 128, SC, 2), dim3(128), 0, stream>>>(
        locs_l, locs_r, pkps, fpk, red, L, T, CT, P);

    pip_final<<<dim3((L + BLK - 1) / BLK), dim3(BLK), 0, stream>>>(
        red, keys, g1_x, g2_x, W1, b1, W2, b2, out, L);
}

// Round 16
// 319.793 us; speedup vs baseline: 2.5686x; 1.4972x over previous
//
#include <hip/hip_runtime.h>
#include <hip/hip_bf16.h>
#include <cstdint>
#include <cstddef>

#define BLK 256     // pack/zero/scatter/final block size
#define DG 12
#define GD 32                     // grid cells per dim
#define NCELL (GD * GD * GD)      // 32768 cells per side
static constexpr float X0_ = -8.0f, INVH_ = 2.0f, H_ = 0.5f;

static constexpr float EPS_ = 0.01f;
// exp(-d/sigma) = exp2(C2*d), C2 = -1/(sigma*ln2), sigma=2.5; C2SQ = C2^2
static constexpr float C2SQ_ = 0.333019070232236f;

typedef __attribute__((ext_vector_type(2))) float v2f;   // packed fp32 (VOP3P)
typedef __attribute__((ext_vector_type(8))) short v8s;   // 8 bf16 (MFMA A/B frag)
typedef __attribute__((ext_vector_type(4))) float v4f;   // MFMA C/D frag

__device__ __forceinline__ int cell_of(float x) {
    int c = (int)floorf((x - X0_) * INVH_);
    return c < 0 ? 0 : (c > GD - 1 ? GD - 1 : c);
}

// ---------------------------------------------------------------------------
// Kernel A: zero the cell-count arrays (2*NCELL ints).
// ---------------------------------------------------------------------------
__global__ __launch_bounds__(BLK) void pip_zero(int* __restrict__ cnt) {
    const int i = blockIdx.x * BLK + threadIdx.x;
    if (i < 2 * NCELL) cnt[i] = 0;
}

// ---------------------------------------------------------------------------
// Kernel B: pack RBF streams + fpk B-frags + init red + count grid cells.
//  pkps[side*P+pr] -> {x0,x1,y0,y1},{z0,z1,h0,h1}  h=C2SQ*|p|^2 (prescaled)
//  fpk[side][tile][lane] -> int4 B-frag of F=[s_x(12),1.0] bf16
//  cnt[side*NCELL+cell]++ for each g1_pos/g2_pos point (argmin grid build).
// ---------------------------------------------------------------------------
__global__ __launch_bounds__(BLK) void pip_pack(
    const float* __restrict__ g1_pos, const float* __restrict__ g2_pos,
    const float* __restrict__ s1_v,   const float* __restrict__ s1_x,
    const float* __restrict__ s2_v,   const float* __restrict__ s2_x,
    float4* __restrict__ pkps, int4* __restrict__ fpk, int* __restrict__ cnt,
    float* __restrict__ red, int N, int T, int L)
{
#pragma clang fp contract(off)
    const int P = T * 16;
    const int tid = blockIdx.x * BLK + threadIdx.x;

    if (tid < 26 * L) red[tid] = 0.f;   // init feature/norm accumulators

    if (tid < 2 * P) {                  // pkps: tid = side*P + pr
        const int side = tid / P;
        const int pr = tid - side * P;
        const float* src = side ? s2_v : s1_v;
        const int n0 = 2 * pr, n1 = 2 * pr + 1;
        float x0 = 1e9f, y0 = 1e9f, z0 = 1e9f, h0 = 1e18f;
        float x1 = 1e9f, y1 = 1e9f, z1 = 1e9f, h1 = 1e18f;
        if (n0 < N) {
            x0 = src[3 * n0]; y0 = src[3 * n0 + 1]; z0 = src[3 * n0 + 2];
            h0 = C2SQ_ * ((x0 * x0 + y0 * y0) + z0 * z0);
        }
        if (n1 < N) {
            x1 = src[3 * n1]; y1 = src[3 * n1 + 1]; z1 = src[3 * n1 + 2];
            h1 = C2SQ_ * ((x1 * x1 + y1 * y1) + z1 * z1);
        }
        pkps[(size_t)tid * 2 + 0] = make_float4(x0, x1, y0, y1);
        pkps[(size_t)tid * 2 + 1] = make_float4(z0, z1, h0, h1);
    } else if (tid < 2 * P + 128 * T) { // fpk B-fragments
        const int u = tid - 2 * P;
        const int side = u / (64 * T);
        const int r = u - side * 64 * T;
        const int t = r >> 6;
        const int ln = r & 63;
        const float* X = side ? s2_x : s1_x;
        const int nb = 32 * t + ((ln >> 4) << 3);
        const int feat = ln & 15;
        int w[4];
#pragma unroll
        for (int d = 0; d < 4; ++d) {
            const int n0 = nb + 2 * d, n1 = nb + 2 * d + 1;
            const float f0 = (n0 < N) ? (feat < 12 ? X[(size_t)n0 * DG + feat] : (feat == 12 ? 1.f : 0.f)) : 0.f;
            const float f1 = (n1 < N) ? (feat < 12 ? X[(size_t)n1 * DG + feat] : (feat == 12 ? 1.f : 0.f)) : 0.f;
            __hip_bfloat162 h = __float22bfloat162_rn(make_float2(f0, f1));
            __builtin_memcpy(&w[d], &h, 4);
        }
        fpk[((size_t)side * T + t) * 64 + ln] = make_int4(w[0], w[1], w[2], w[3]);
    } else if (tid < 2 * P + 128 * T + 2 * N) {  // grid cell counting
        const int u = tid - (2 * P + 128 * T);
        const int side = u / N;
        const int n = u - side * N;
        const float* src = side ? g2_pos : g1_pos;
        const float x = src[3 * n], y = src[3 * n + 1], z = src[3 * n + 2];
        const int c = (cell_of(x) * GD + cell_of(y)) * GD + cell_of(z);
        atomicAdd(&cnt[side * NCELL + c], 1);
    }
}

// ---------------------------------------------------------------------------
// Kernel C: exclusive scan of counts -> offsets; counts become cursors.
// 1024 threads; per-thread 64-cell block sum; Hillis-Steele tree scan in LDS.
// ---------------------------------------------------------------------------
__global__ __launch_bounds__(1024) void pip_scan(
    int* __restrict__ cnt, int* __restrict__ off)
{
    __shared__ int lds[1024];
    const int t = threadIdx.x;
    const int per = (2 * NCELL) / 1024;   // 64
    int s = 0;
#pragma unroll 8
    for (int i = 0; i < per; ++i) s += cnt[t * per + i];
    lds[t] = s;
    __syncthreads();
    for (int o = 1; o < 1024; o <<= 1) {
        const int v = (t >= o) ? lds[t - o] : 0;
        __syncthreads();
        lds[t] += v;
        __syncthreads();
    }
    int base = lds[t] - s;   // exclusive prefix of this thread's block
    for (int i = 0; i < per; ++i) {
        const int idx = t * per + i;
        const int c = cnt[idx];
        off[idx] = base;
        cnt[idx] = base;      // cursor init; scatter bumps to end offset
        base += c;
    }
}

// ---------------------------------------------------------------------------
// Kernel D: scatter points into grid order. grid_pts[slot]={x,y,z,|p|^2/2},
// grid_id[slot]=n. Slots are globally disjoint (scan spans both sides).
// pn2h uses the exact reference arithmetic ((x*x+y*y)+z*z, no fma) * 0.5.
// ---------------------------------------------------------------------------
__global__ __launch_bounds__(BLK) void pip_scatter(
    const float* __restrict__ g1_pos, const float* __restrict__ g2_pos,
    int* __restrict__ cursor, float4* __restrict__ grid_pts,
    int* __restrict__ grid_id, int N)
{
#pragma clang fp contract(off)
    const int u = blockIdx.x * BLK + threadIdx.x;
    if (u >= 2 * N) return;
    const int side = u / N;
    const int n = u - side * N;
    const float* src = side ? g2_pos : g1_pos;
    const float x = src[3 * n], y = src[3 * n + 1], z = src[3 * n + 2];
    const float h = 0.5f * ((x * x + y * y) + z * z);
    const int c = (cell_of(x) * GD + cell_of(y)) * GD + cell_of(z);
    const int slot = atomicAdd(&cursor[side * NCELL + c], 1);
    grid_pts[slot] = make_float4(x, y, z, h);
    grid_id[slot] = n;
}

// ---------------------------------------------------------------------------
// Kernel E: exact NN via grid — two-level parallel. One WAVE per (query,side),
// 4 waves/block. All lanes share the query, so cell ranges are wave-uniform.
// The (2R+1)^3 cube = (2R+1)^2 contiguous z-RUNS (CSR z-contiguity:
// off[col,zlo]..ends[col,zhi]). Phase 1: lanes gather run bounds in PARALLEL
// (lane k -> run base+k). Phase 2: per run, broadcast bounds via 2 shfl
// (register-only), scan points LANE-PARALLEL j=st+lane, j+=64. No serial
// latency chain (R14 was wave-serial cells; R15 was lane-serial points).
// Every point gets true-d2 (stop bound) AND the bit-exact half-scale trick
// key ((nqh+pn2h)-fma-dot = reference fp32 formula). Stop when
// (R*h)^2 > best_true + 1e-3 (covers trick-vs-true skew <= ~3e-5; clamped
// points only exceed their cell's lower bound). R=GD = full grid fallback.
// ---------------------------------------------------------------------------
__global__ __launch_bounds__(BLK) void pip_nn(
    const float* __restrict__ locs_l, const float* __restrict__ locs_r,
    const int* __restrict__ off, const int* __restrict__ ends,
    const float4* __restrict__ grid_pts, const int* __restrict__ grid_id,
    unsigned long long* __restrict__ keys, int L)
{
#pragma clang fp contract(off)
    const int lane = threadIdx.x & 63;
    const int id = blockIdx.x * 4 + (threadIdx.x >> 6);   // [0, 2L)
    const int side = id / L;
    const int lq = id - side * L;

    const float* __restrict__ locs = side ? locs_r : locs_l;
    const float qx = locs[3 * lq + 0];
    const float qy = locs[3 * lq + 1];
    const float qz = locs[3 * lq + 2];
    const float nqh = 0.5f * ((qx * qx + qy * qy) + qz * qz);

    const int cx = cell_of(qx), cy = cell_of(qy), cz = cell_of(qz);
    const int cb = side * NCELL;

    float bt = 3.4e38f;                 // best true d2 (per-lane until reduce)
    unsigned long long bk = ~0ull;      // best (trick d2h bits << 32 | idx)

    for (int R = 1; R <= GD; R <<= 1) {
        const int s = 2 * R + 1;
        const int runs = s * s;                       // (a,b) columns
        const int zlo = max(cz - R, 0), zhi = min(cz + R, GD - 1);
        for (int base = 0; base < runs; base += 64) {
            const int my = base + lane;
            int st = 0, en = 0;
            if (my < runs) {                          // phase 1: parallel bound fetch
                const int a = my / s;
                const int b = my - a * s;
                const int ca = cx + a - R;
                const int cbq = cy + b - R;
                if (ca >= 0 && ca < GD && cbq >= 0 && cbq < GD) {
                    const int cbase = cb + (ca * GD + cbq) * GD;
                    st = off[cbase + zlo];
                    en = ends[cbase + zhi];
                }
            }
            const int nk = (runs - base < 64) ? (runs - base) : 64;
            for (int k = 0; k < nk; ++k) {            // phase 2: broadcast + scan
                const int stk = __shfl(st, k);
                const int enk = __shfl(en, k);
                for (int j = stk + lane; j < enk; j += 64) {
                    const float4 gp = grid_pts[j];
                    const float dx = qx - gp.x, dy = qy - gp.y, dz = qz - gp.z;
                    const float dt = fmaf(dx, dx, fmaf(dy, dy, dz * dz));
                    bt = fminf(bt, dt);
                    const float dot = fmaf(qz, gp.z, fmaf(qy, gp.y, qx * gp.x));
                    const float d2h = (nqh + gp.w) - dot;   // exact ref formula (half-scale)
                    const unsigned long long key =
                        ((unsigned long long)__float_as_uint(d2h) << 32) |
                        (unsigned long long)(unsigned)grid_id[j];
                    bk = key < bk ? key : bk;
                }
            }
        }
        // wave-reduce best_true; check stop bound
        for (int m = 1; m < 64; m <<= 1) bt = fminf(bt, __shfl_xor(bt, m));
        const float bnd = (float)R * H_;
        if (bnd * bnd > bt + 1e-3f) break;
    }

    for (int m = 1; m < 64; m <<= 1) {
        const unsigned long long o = __shfl_xor(bk, m);
        bk = o < bk ? o : bk;
    }
    if (lane == 0) keys[(size_t)side * L + lq] = bk;
}

// ---------------------------------------------------------------------------
// Kernel F: RBF partial scans (argmin handled by pip_nn).
// Block = 128 thr = 2 waves; one side (blockIdx.z), one chunk (blockIdx.y).
// Per dp-group: 2 vector loads, packed prescaled dot-form distances,
// w = exp2(-sqrt(t)), 1-inst v_perm bf16 truncation pack, 4 MFMAs/tile.
// Feature sums accumulate via device atomicAdd into red.
// ---------------------------------------------------------------------------
__global__ __launch_bounds__(128, 4) void pip_partial(
    const float* __restrict__ locs_l, const float* __restrict__ locs_r,
    const float4* __restrict__ pkps, const int4* __restrict__ fpk,
    float* __restrict__ red, int L, int T, int CT, int P)
{
#pragma clang fp contract(off)
    const int lane = threadIdx.x & 63;
    const int wv = threadIdx.x >> 6;
    const int side = blockIdx.z;
    const int qbase = blockIdx.x * 128 + wv * 64;

    const float* __restrict__ locs = side ? locs_r : locs_l;

    // fragment-role queries: q = qbase + 16*mt + (lane&15); prescaled consts
    float nq2[4], m2x[4], m2y[4], m2z[4];
#pragma unroll
    for (int mt = 0; mt < 4; ++mt) {
        const int qm = qbase + 16 * mt + (lane & 15);
        const float a = locs[3 * qm + 0];
        const float b = locs[3 * qm + 1];
        const float c = locs[3 * qm + 2];
        nq2[mt] = C2SQ_ * ((a * a + b * b) + c * c);
        const float s2 = -2.0f * C2SQ_;
        m2x[mt] = s2 * a; m2y[mt] = s2 * b; m2z[mt] = s2 * c;
    }

    v4f cC[4];
#pragma unroll
    for (int mt = 0; mt < 4; ++mt) cC[mt] = (v4f)0.f;

    const float4* __restrict__ pkpb = pkps + (size_t)side * P * 2;

    const int t0 = blockIdx.y * CT;
    const int t1 = (t0 + CT < T) ? (t0 + CT) : T;

    for (int tg = t0; tg < t1; ++tg) {
        const v8s b = ((const v8s*)fpk)[((size_t)side * T + tg) * 64 + lane];
        union AF { int i[4]; v8s s; };
        AF af[4];
        const int pg0 = tg * 16 + ((lane >> 4) << 2);   // this lane's 4 point-pairs

#pragma unroll
        for (int dp = 0; dp < 4; ++dp) {
            const float4 FXY = pkpb[(size_t)(pg0 + dp) * 2 + 0];
            const float4 FZH = pkpb[(size_t)(pg0 + dp) * 2 + 1];
            const v2f px = {FXY.x, FXY.y}, py = {FXY.z, FXY.w};
            const v2f pz = {FZH.x, FZH.y}, ph = {FZH.z, FZH.w};
#pragma unroll
            for (int mt = 0; mt < 4; ++mt) {
                const v2f mx = {m2x[mt], m2x[mt]};
                const v2f my = {m2y[mt], m2y[mt]};
                const v2f mz = {m2z[mt], m2z[mt]};
                const v2f s  = nq2[mt] + ph;
                v2f t = __builtin_elementwise_fma(mz, pz,
                          __builtin_elementwise_fma(my, py,
                            __builtin_elementwise_fma(mx, px, s)));
                t = __builtin_elementwise_max(t, (v2f)0.f);   // cancellation guard
                const float w0 = __builtin_amdgcn_exp2f(-__builtin_amdgcn_sqrtf(t.x));
                const float w1 = __builtin_amdgcn_exp2f(-__builtin_amdgcn_sqrtf(t.y));
                af[mt].i[dp] = (int)__builtin_amdgcn_perm(
                    __float_as_uint(w1), __float_as_uint(w0), 0x07060302u);
            }
        }

#pragma unroll
        for (int mt = 0; mt < 4; ++mt)
            cC[mt] = __builtin_amdgcn_mfma_f32_16x16x32_bf16(af[mt].s, b, cC[mt], 0, 0, 0);
    }

    const int feat = lane & 15;
    if (feat < 13) {
        const int slot = side * 13 + feat;
        // C/D layout: col(=feat)=lane&15, row(=q within 16-tile)=(lane>>4)*4+reg
#pragma unroll
        for (int mt = 0; mt < 4; ++mt)
#pragma unroll
            for (int r = 0; r < 4; ++r) {
                const int q = qbase + 16 * mt + ((lane >> 4) << 2) + r;
                atomicAdd(&red[(size_t)slot * L + q], cC[mt][r]);
            }
    }
}

__device__ __forceinline__ float tanh_pos(float x) {
    const float t = __expf(-2.f * x);
    return (1.f - t) / (1.f + t);
}

// ---------------------------------------------------------------------------
// Kernel G: gather nearest-node feats + 50->50->1 MLP. Thread = one query l.
// ---------------------------------------------------------------------------
__global__ __launch_bounds__(BLK) void pip_final(
    const float* __restrict__ red, const unsigned long long* __restrict__ keys,
    const float* __restrict__ g1_x, const float* __restrict__ g2_x,
    const float* __restrict__ W1, const float* __restrict__ b1,
    const float* __restrict__ W2, const float* __restrict__ b2,
    float* __restrict__ out, int L)
{
#pragma clang fp contract(off)
    const int l = blockIdx.x * BLK + threadIdx.x;
    if (l >= L) return;

    const unsigned idxL = (unsigned)(keys[l] & 0xffffffffull);
    const unsigned idxR = (unsigned)(keys[(size_t)L + l] & 0xffffffffull);
    const float normL = red[(size_t)12 * L + (size_t)l] + EPS_;
    const float normR = red[(size_t)25 * L + (size_t)l] + EPS_;

    float x[50];
    {
        const float4* f = (const float4*)(g1_x + (size_t)idxL * DG);
        const float4 f0 = f[0], f1 = f[1], f2 = f[2];
        x[0] = f0.x; x[1] = f0.y; x[2]  = f0.z; x[3]  = f0.w;
        x[4] = f1.x; x[5] = f1.y; x[6]  = f1.z; x[7]  = f1.w;
        x[8] = f2.x; x[9] = f2.y; x[10] = f2.z; x[11] = f2.w;
    }
#pragma unroll
    for (int k = 0; k < DG; ++k) x[12 + k] = red[(size_t)k * L + (size_t)l] / normL;
    x[24] = tanh_pos(normL);
    {
        const float4* f = (const float4*)(g2_x + (size_t)idxR * DG);
        const float4 f0 = f[0], f1 = f[1], f2 = f[2];
        x[25] = f0.x; x[26] = f0.y; x[27] = f0.z; x[28] = f0.w;
        x[29] = f1.x; x[30] = f1.y; x[31] = f1.z; x[32] = f1.w;
        x[33] = f2.x; x[34] = f2.y; x[35] = f2.z; x[36] = f2.w;
    }
#pragma unroll
    for (int k = 0; k < DG; ++k) x[37 + k] = red[(size_t)(13 + k) * L + (size_t)l] / normR;
    x[49] = tanh_pos(normR);

    float h[50];
#pragma unroll
    for (int j = 0; j < 50; ++j) h[j] = b1[j];
#pragma unroll
    for (int k = 0; k < 50; ++k) {
        const float xk = x[k];
#pragma unroll
        for (int j = 0; j < 50; ++j) h[j] = fmaf(xk, W1[k * 50 + j], h[j]);
    }
    float o = b2[0];
#pragma unroll
    for (int j = 0; j < 50; ++j) o = fmaf(fmaxf(h[j], 0.f), W2[j], o);
    out[l] = o;
}

// ---------------------------------------------------------------------------
extern "C" void kernel_launch(void* const* d_in, const int* in_sizes, int n_in,
                              void* d_out, int out_size, void* d_ws, size_t ws_size,
                              hipStream_t stream) {
    const float* locs_l = (const float*)d_in[0];
    const float* locs_r = (const float*)d_in[1];
    const float* g1_pos = (const float*)d_in[2];
    const float* g1_x   = (const float*)d_in[3];
    const float* g2_pos = (const float*)d_in[4];
    const float* g2_x   = (const float*)d_in[5];
    const float* s1_v   = (const float*)d_in[6];
    const float* s1_x   = (const float*)d_in[7];
    const float* s2_v   = (const float*)d_in[8];
    const float* s2_x   = (const float*)d_in[9];
    const float* W1     = (const float*)d_in[10];
    const float* b1     = (const float*)d_in[11];
    const float* W2     = (const float*)d_in[12];
    const float* b2     = (const float*)d_in[13];
    float* out = (float*)d_out;
    float* ws  = (float*)d_ws;

    const int L = in_sizes[0] / 3;   // 4096
    const int N = in_sizes[2] / 3;   // 40000
    const int T = (N + 31) / 32;     // 32-point tiles (1250, exact)
    const int P = T * 16;            // point pairs

    // ws layout (floats):
    //  [pkps: 256T][fpk: 512T][red: 26L][keys: 2L u64]
    //  [cnt/cursor/end: 2*NCELL int][off: 2*NCELL int][grid_pts: 8N][grid_id: 2N]
    const size_t o_fpk  = (size_t)256 * T;
    const size_t o_red  = (size_t)768 * T;
    const size_t o_keys = o_red + (size_t)26 * L;
    const size_t o_cnt  = o_keys + (size_t)4 * L;
    const size_t o_off  = o_cnt + (size_t)2 * NCELL;
    const size_t o_gpts = o_off + (size_t)2 * NCELL;
    const size_t o_gid  = o_gpts + (size_t)8 * N;

    float4* pkps = (float4*)ws;
    int4*   fpk  = (int4*)(ws + o_fpk);
    float*  red  = ws + o_red;
    unsigned long long* keys = (unsigned long long*)(ws + o_keys);
    int*    cnt  = (int*)(ws + o_cnt);
    int*    off  = (int*)(ws + o_off);
    float4* gpts = (float4*)(ws + o_gpts);
    int*    gid  = (int*)(ws + o_gid);

    const int CT = 40;                       // tiles per chunk
    const int SC = (T + CT - 1) / CT;        // 32 chunks -> grid 32 x 32 x 2

    pip_zero<<<dim3((2 * NCELL + BLK - 1) / BLK), dim3(BLK), 0, stream>>>(cnt);

    const int ptasks = 2 * P + 128 * T + 2 * N;
    pip_pack<<<dim3((ptasks + BLK - 1) / BLK), dim3(BLK), 0, stream>>>(
        g1_pos, g2_pos, s1_v, s1_x, s2_v, s2_x, pkps, fpk, cnt, red, N, T, L);

    pip_scan<<<dim3(1), dim3(1024), 0, stream>>>(cnt, off);

    pip_scatter<<<dim3((2 * N + BLK - 1) / BLK), dim3(BLK), 0, stream>>>(
        g1_pos, g2_pos, cnt, gpts, gid, N);

    pip_nn<<<dim3(2 * L / 4), dim3(BLK), 0, stream>>>(
        locs_l, locs_r, off, cnt, gpts, gid, keys, L);

    pip_partial<<<dim3(L / 128, SC, 2), dim3(128), 0, stream>>>(
        locs_l, locs_r, pkps, fpk, red, L, T, CT, P);

    pip_final<<<dim3((L + BLK - 1) / BLK), dim3(BLK), 0, stream>>>(
        red, keys, g1_x, g2_x, W1, b1, W2, b2, out, L);
}

// Round 17
// 318.013 us; speedup vs baseline: 2.5829x; 1.0056x over previous
//
#include <hip/hip_runtime.h>
#include <hip/hip_bf16.h>
#include <cstdint>
#include <cstddef>

#define BLK 256     // pack/scatter/final block size
#define DG 12
#define GD 32                     // grid cells per dim
#define NCELL (GD * GD * GD)      // 32768 cells per side
static constexpr float X0_ = -8.0f, INVH_ = 2.0f, H_ = 0.5f;

static constexpr float EPS_ = 0.01f;
// exp(-d/sigma) = exp2(C2*d), C2 = -1/(sigma*ln2), sigma=2.5; C2SQ = C2^2
static constexpr float C2SQ_ = 0.333019070232236f;

typedef __attribute__((ext_vector_type(2))) float v2f;   // packed fp32 (VOP3P)
typedef __attribute__((ext_vector_type(8))) short v8s;   // 8 bf16 (MFMA A/B frag)
typedef __attribute__((ext_vector_type(4))) float v4f;   // MFMA C/D frag

__device__ __forceinline__ int cell_of(float x) {
    int c = (int)floorf((x - X0_) * INVH_);
    return c < 0 ? 0 : (c > GD - 1 ? GD - 1 : c);
}

// ---------------------------------------------------------------------------
// Kernel B: pack RBF streams + fpk B-frags + count grid cells.
// (red zeroed by hipMemsetAsync; keys need no init — nn writes unconditionally.)
//  pkps[side*P+pr] -> {x0,x1,y0,y1},{z0,z1,h0,h1}  h=C2SQ*|p|^2 (prescaled)
//  fpk[side][tile][lane] -> int4 B-frag of F=[s_x(12),1.0] bf16
//  cnt[side*NCELL+cell]++ for each g1_pos/g2_pos point (argmin grid build).
// ---------------------------------------------------------------------------
__global__ __launch_bounds__(BLK) void pip_pack(
    const float* __restrict__ g1_pos, const float* __restrict__ g2_pos,
    const float* __restrict__ s1_v,   const float* __restrict__ s1_x,
    const float* __restrict__ s2_v,   const float* __restrict__ s2_x,
    float4* __restrict__ pkps, int4* __restrict__ fpk, int* __restrict__ cnt,
    int N, int T)
{
#pragma clang fp contract(off)
    const int P = T * 16;
    const int tid = blockIdx.x * BLK + threadIdx.x;

    if (tid < 2 * P) {                  // pkps: tid = side*P + pr
        const int side = tid / P;
        const int pr = tid - side * P;
        const float* src = side ? s2_v : s1_v;
        const int n0 = 2 * pr, n1 = 2 * pr + 1;
        float x0 = 1e9f, y0 = 1e9f, z0 = 1e9f, h0 = 1e18f;
        float x1 = 1e9f, y1 = 1e9f, z1 = 1e9f, h1 = 1e18f;
        if (n0 < N) {
            x0 = src[3 * n0]; y0 = src[3 * n0 + 1]; z0 = src[3 * n0 + 2];
            h0 = C2SQ_ * ((x0 * x0 + y0 * y0) + z0 * z0);
        }
        if (n1 < N) {
            x1 = src[3 * n1]; y1 = src[3 * n1 + 1]; z1 = src[3 * n1 + 2];
            h1 = C2SQ_ * ((x1 * x1 + y1 * y1) + z1 * z1);
        }
        pkps[(size_t)tid * 2 + 0] = make_float4(x0, x1, y0, y1);
        pkps[(size_t)tid * 2 + 1] = make_float4(z0, z1, h0, h1);
    } else if (tid < 2 * P + 128 * T) { // fpk B-fragments
        const int u = tid - 2 * P;
        const int side = u / (64 * T);
        const int r = u - side * 64 * T;
        const int t = r >> 6;
        const int ln = r & 63;
        const float* X = side ? s2_x : s1_x;
        const int nb = 32 * t + ((ln >> 4) << 3);
        const int feat = ln & 15;
        int w[4];
#pragma unroll
        for (int d = 0; d < 4; ++d) {
            const int n0 = nb + 2 * d, n1 = nb + 2 * d + 1;
            const float f0 = (n0 < N) ? (feat < 12 ? X[(size_t)n0 * DG + feat] : (feat == 12 ? 1.f : 0.f)) : 0.f;
            const float f1 = (n1 < N) ? (feat < 12 ? X[(size_t)n1 * DG + feat] : (feat == 12 ? 1.f : 0.f)) : 0.f;
            __hip_bfloat162 h = __float22bfloat162_rn(make_float2(f0, f1));
            __builtin_memcpy(&w[d], &h, 4);
        }
        fpk[((size_t)side * T + t) * 64 + ln] = make_int4(w[0], w[1], w[2], w[3]);
    } else if (tid < 2 * P + 128 * T + 2 * N) {  // grid cell counting
        const int u = tid - (2 * P + 128 * T);
        const int side = u / N;
        const int n = u - side * N;
        const float* src = side ? g2_pos : g1_pos;
        const float x = src[3 * n], y = src[3 * n + 1], z = src[3 * n + 2];
        const int c = (cell_of(x) * GD + cell_of(y)) * GD + cell_of(z);
        atomicAdd(&cnt[side * NCELL + c], 1);
    }
}

// ---------------------------------------------------------------------------
// Kernel C: exclusive scan of counts -> offsets; counts become cursors.
// 1024 threads; per-thread 64-cell block sum; Hillis-Steele tree scan in LDS.
// ---------------------------------------------------------------------------
__global__ __launch_bounds__(1024) void pip_scan(
    int* __restrict__ cnt, int* __restrict__ off)
{
    __shared__ int lds[1024];
    const int t = threadIdx.x;
    const int per = (2 * NCELL) / 1024;   // 64
    int s = 0;
#pragma unroll 8
    for (int i = 0; i < per; ++i) s += cnt[t * per + i];
    lds[t] = s;
    __syncthreads();
    for (int o = 1; o < 1024; o <<= 1) {
        const int v = (t >= o) ? lds[t - o] : 0;
        __syncthreads();
        lds[t] += v;
        __syncthreads();
    }
    int base = lds[t] - s;   // exclusive prefix of this thread's block
    for (int i = 0; i < per; ++i) {
        const int idx = t * per + i;
        const int c = cnt[idx];
        off[idx] = base;
        cnt[idx] = base;      // cursor init; scatter bumps to end offset
        base += c;
    }
}

// ---------------------------------------------------------------------------
// Kernel D: scatter points into grid order. grid_pts[slot]={x,y,z,|p|^2/2},
// grid_id[slot]=n. Slots are globally disjoint (scan spans both sides).
// pn2h uses the exact reference arithmetic ((x*x+y*y)+z*z, no fma) * 0.5.
// ---------------------------------------------------------------------------
__global__ __launch_bounds__(BLK) void pip_scatter(
    const float* __restrict__ g1_pos, const float* __restrict__ g2_pos,
    int* __restrict__ cursor, float4* __restrict__ grid_pts,
    int* __restrict__ grid_id, int N)
{
#pragma clang fp contract(off)
    const int u = blockIdx.x * BLK + threadIdx.x;
    if (u >= 2 * N) return;
    const int side = u / N;
    const int n = u - side * N;
    const float* src = side ? g2_pos : g1_pos;
    const float x = src[3 * n], y = src[3 * n + 1], z = src[3 * n + 2];
    const float h = 0.5f * ((x * x + y * y) + z * z);
    const int c = (cell_of(x) * GD + cell_of(y)) * GD + cell_of(z);
    const int slot = atomicAdd(&cursor[side * NCELL + c], 1);
    grid_pts[slot] = make_float4(x, y, z, h);
    grid_id[slot] = n;
}

// ---------------------------------------------------------------------------
// Kernel E (FUSED): block-role split.
//  blockIdx.x < nbp : RBF partial chunk (decode bx/sc/side) — MFMA path.
//  blockIdx.x >= nbp: grid-NN, 2 waves/block, one (query,side) per wave.
// Rationale: nn waves are gather/latency-bound with ~no VALU demand; at
// VGPR~60 residency (~4096 blocks) covers all partial blocks + nn blocks,
// so nn executes inside partial's idle issue slots (R16: serial nn ~39 us).
// NN: two-level parallel (lanes gather z-run bounds in parallel; per run,
// 2 shfl broadcast + lane-parallel point scan). Every point gets true-d2
// (stop bound) AND the bit-exact half-scale trick key ((nqh+pn2h)-fma-dot
// = reference fp32 formula; u64 min = first-index tiebreak). Stop when
// (R*h)^2 > best_true + 1e-3 (trick-vs-true skew <= ~3e-5). R=GD = full grid.
// ---------------------------------------------------------------------------
__global__ __launch_bounds__(128, 4) void pip_fused(
    const float* __restrict__ locs_l, const float* __restrict__ locs_r,
    const float4* __restrict__ pkps, const int4* __restrict__ fpk,
    const int* __restrict__ off, const int* __restrict__ ends,
    const float4* __restrict__ grid_pts, const int* __restrict__ grid_id,
    float* __restrict__ red, unsigned long long* __restrict__ keys,
    int L, int T, int CT, int P, int SC, int nbp)
{
#pragma clang fp contract(off)
    const int lane = threadIdx.x & 63;
    const int wv = threadIdx.x >> 6;

    if ((int)blockIdx.x < nbp) {
        // =================== RBF partial path ===================
        const int id = blockIdx.x;
        const int qblocks = L / 128;
        const int bx = id % qblocks;
        const int rem = id / qblocks;
        const int sc = rem % SC;
        const int side = rem / SC;
        const int qbase = bx * 128 + wv * 64;

        const float* __restrict__ locs = side ? locs_r : locs_l;

        float nq2[4], m2x[4], m2y[4], m2z[4];
#pragma unroll
        for (int mt = 0; mt < 4; ++mt) {
            const int qm = qbase + 16 * mt + (lane & 15);
            const float a = locs[3 * qm + 0];
            const float b = locs[3 * qm + 1];
            const float c = locs[3 * qm + 2];
            nq2[mt] = C2SQ_ * ((a * a + b * b) + c * c);
            const float s2 = -2.0f * C2SQ_;
            m2x[mt] = s2 * a; m2y[mt] = s2 * b; m2z[mt] = s2 * c;
        }

        v4f cC[4];
#pragma unroll
        for (int mt = 0; mt < 4; ++mt) cC[mt] = (v4f)0.f;

        const float4* __restrict__ pkpb = pkps + (size_t)side * P * 2;

        const int t0 = sc * CT;
        const int t1 = (t0 + CT < T) ? (t0 + CT) : T;

        for (int tg = t0; tg < t1; ++tg) {
            const v8s b = ((const v8s*)fpk)[((size_t)side * T + tg) * 64 + lane];
            union AF { int i[4]; v8s s; };
            AF af[4];
            const int pg0 = tg * 16 + ((lane >> 4) << 2);

#pragma unroll
            for (int dp = 0; dp < 4; ++dp) {
                const float4 FXY = pkpb[(size_t)(pg0 + dp) * 2 + 0];
                const float4 FZH = pkpb[(size_t)(pg0 + dp) * 2 + 1];
                const v2f px = {FXY.x, FXY.y}, py = {FXY.z, FXY.w};
                const v2f pz = {FZH.x, FZH.y}, ph = {FZH.z, FZH.w};
#pragma unroll
                for (int mt = 0; mt < 4; ++mt) {
                    const v2f mx = {m2x[mt], m2x[mt]};
                    const v2f my = {m2y[mt], m2y[mt]};
                    const v2f mz = {m2z[mt], m2z[mt]};
                    const v2f s  = nq2[mt] + ph;
                    v2f t = __builtin_elementwise_fma(mz, pz,
                              __builtin_elementwise_fma(my, py,
                                __builtin_elementwise_fma(mx, px, s)));
                    t = __builtin_elementwise_max(t, (v2f)0.f);   // cancellation guard
                    const float w0 = __builtin_amdgcn_exp2f(-__builtin_amdgcn_sqrtf(t.x));
                    const float w1 = __builtin_amdgcn_exp2f(-__builtin_amdgcn_sqrtf(t.y));
                    af[mt].i[dp] = (int)__builtin_amdgcn_perm(
                        __float_as_uint(w1), __float_as_uint(w0), 0x07060302u);
                }
            }

#pragma unroll
            for (int mt = 0; mt < 4; ++mt)
                cC[mt] = __builtin_amdgcn_mfma_f32_16x16x32_bf16(af[mt].s, b, cC[mt], 0, 0, 0);
        }

        const int feat = lane & 15;
        if (feat < 13) {
            const int slot = side * 13 + feat;
            // C/D layout: col(=feat)=lane&15, row=(lane>>4)*4+reg
#pragma unroll
            for (int mt = 0; mt < 4; ++mt)
#pragma unroll
                for (int r = 0; r < 4; ++r) {
                    const int q = qbase + 16 * mt + ((lane >> 4) << 2) + r;
                    atomicAdd(&red[(size_t)slot * L + q], cC[mt][r]);
                }
        }
    } else {
        // =================== grid-NN path ===================
        const int qsid = (blockIdx.x - nbp) * 2 + wv;   // [0, 2L)
        const int side = qsid / L;
        const int lq = qsid - side * L;

        const float* __restrict__ locs = side ? locs_r : locs_l;
        const float qx = locs[3 * lq + 0];
        const float qy = locs[3 * lq + 1];
        const float qz = locs[3 * lq + 2];
        const float nqh = 0.5f * ((qx * qx + qy * qy) + qz * qz);

        const int cx = cell_of(qx), cy = cell_of(qy), cz = cell_of(qz);
        const int cb = side * NCELL;

        float bt = 3.4e38f;
        unsigned long long bk = ~0ull;

        for (int R = 1; R <= GD; R <<= 1) {
            const int s = 2 * R + 1;
            const int runs = s * s;
            const int zlo = max(cz - R, 0), zhi = min(cz + R, GD - 1);
            for (int base = 0; base < runs; base += 64) {
                const int my = base + lane;
                int st = 0, en = 0;
                if (my < runs) {                          // phase 1: parallel bound fetch
                    const int a = my / s;
                    const int b = my - a * s;
                    const int ca = cx + a - R;
                    const int cbq = cy + b - R;
                    if (ca >= 0 && ca < GD && cbq >= 0 && cbq < GD) {
                        const int cbase = cb + (ca * GD + cbq) * GD;
                        st = off[cbase + zlo];
                        en = ends[cbase + zhi];
                    }
                }
                const int nk = (runs - base < 64) ? (runs - base) : 64;
                for (int k = 0; k < nk; ++k) {            // phase 2: broadcast + scan
                    const int stk = __shfl(st, k);
                    const int enk = __shfl(en, k);
                    for (int j = stk + lane; j < enk; j += 64) {
                        const float4 gp = grid_pts[j];
                        const float dx = qx - gp.x, dy = qy - gp.y, dz = qz - gp.z;
                        const float dt = fmaf(dx, dx, fmaf(dy, dy, dz * dz));
                        bt = fminf(bt, dt);
                        const float dot = fmaf(qz, gp.z, fmaf(qy, gp.y, qx * gp.x));
                        const float d2h = (nqh + gp.w) - dot;   // exact ref formula (half-scale)
                        const unsigned long long key =
                            ((unsigned long long)__float_as_uint(d2h) << 32) |
                            (unsigned long long)(unsigned)grid_id[j];
                        bk = key < bk ? key : bk;
                    }
                }
            }
            for (int m = 1; m < 64; m <<= 1) bt = fminf(bt, __shfl_xor(bt, m));
            const float bnd = (float)R * H_;
            if (bnd * bnd > bt + 1e-3f) break;
        }

        for (int m = 1; m < 64; m <<= 1) {
            const unsigned long long o = __shfl_xor(bk, m);
            bk = o < bk ? o : bk;
        }
        if (lane == 0) keys[(size_t)side * L + lq] = bk;
    }
}

__device__ __forceinline__ float tanh_pos(float x) {
    const float t = __expf(-2.f * x);
    return (1.f - t) / (1.f + t);
}

// ---------------------------------------------------------------------------
// Kernel G: gather nearest-node feats + 50->50->1 MLP. Thread = one query l.
// ---------------------------------------------------------------------------
__global__ __launch_bounds__(BLK) void pip_final(
    const float* __restrict__ red, const unsigned long long* __restrict__ keys,
    const float* __restrict__ g1_x, const float* __restrict__ g2_x,
    const float* __restrict__ W1, const float* __restrict__ b1,
    const float* __restrict__ W2, const float* __restrict__ b2,
    float* __restrict__ out, int L)
{
#pragma clang fp contract(off)
    const int l = blockIdx.x * BLK + threadIdx.x;
    if (l >= L) return;

    const unsigned idxL = (unsigned)(keys[l] & 0xffffffffull);
    const unsigned idxR = (unsigned)(keys[(size_t)L + l] & 0xffffffffull);
    const float normL = red[(size_t)12 * L + (size_t)l] + EPS_;
    const float normR = red[(size_t)25 * L + (size_t)l] + EPS_;

    float x[50];
    {
        const float4* f = (const float4*)(g1_x + (size_t)idxL * DG);
        const float4 f0 = f[0], f1 = f[1], f2 = f[2];
        x[0] = f0.x; x[1] = f0.y; x[2]  = f0.z; x[3]  = f0.w;
        x[4] = f1.x; x[5] = f1.y; x[6]  = f1.z; x[7]  = f1.w;
        x[8] = f2.x; x[9] = f2.y; x[10] = f2.z; x[11] = f2.w;
    }
#pragma unroll
    for (int k = 0; k < DG; ++k) x[12 + k] = red[(size_t)k * L + (size_t)l] / normL;
    x[24] = tanh_pos(normL);
    {
        const float4* f = (const float4*)(g2_x + (size_t)idxR * DG);
        const float4 f0 = f[0], f1 = f[1], f2 = f[2];
        x[25] = f0.x; x[26] = f0.y; x[27] = f0.z; x[28] = f0.w;
        x[29] = f1.x; x[30] = f1.y; x[31] = f1.z; x[32] = f1.w;
        x[33] = f2.x; x[34] = f2.y; x[35] = f2.z; x[36] = f2.w;
    }
#pragma unroll
    for (int k = 0; k < DG; ++k) x[37 + k] = red[(size_t)(13 + k) * L + (size_t)l] / normR;
    x[49] = tanh_pos(normR);

    float h[50];
#pragma unroll
    for (int j = 0; j < 50; ++j) h[j] = b1[j];
#pragma unroll
    for (int k = 0; k < 50; ++k) {
        const float xk = x[k];
#pragma unroll
        for (int j = 0; j < 50; ++j) h[j] = fmaf(xk, W1[k * 50 + j], h[j]);
    }
    float o = b2[0];
#pragma unroll
    for (int j = 0; j < 50; ++j) o = fmaf(fmaxf(h[j], 0.f), W2[j], o);
    out[l] = o;
}

// ---------------------------------------------------------------------------
extern "C" void kernel_launch(void* const* d_in, const int* in_sizes, int n_in,
                              void* d_out, int out_size, void* d_ws, size_t ws_size,
                              hipStream_t stream) {
    const float* locs_l = (const float*)d_in[0];
    const float* locs_r = (const float*)d_in[1];
    const float* g1_pos = (const float*)d_in[2];
    const float* g1_x   = (const float*)d_in[3];
    const float* g2_pos = (const float*)d_in[4];
    const float* g2_x   = (const float*)d_in[5];
    const float* s1_v   = (const float*)d_in[6];
    const float* s1_x   = (const float*)d_in[7];
    const float* s2_v   = (const float*)d_in[8];
    const float* s2_x   = (const float*)d_in[9];
    const float* W1     = (const float*)d_in[10];
    const float* b1     = (const float*)d_in[11];
    const float* W2     = (const float*)d_in[12];
    const float* b2     = (const float*)d_in[13];
    float* out = (float*)d_out;
    float* ws  = (float*)d_ws;

    const int L = in_sizes[0] / 3;   // 4096
    const int N = in_sizes[2] / 3;   // 40000
    const int T = (N + 31) / 32;     // 32-point tiles (1250, exact)
    const int P = T * 16;            // point pairs

    // ws layout (floats):
    //  [pkps: 256T][fpk: 512T][red: 26L][keys: 2L u64]
    //  [cnt/cursor/end: 2*NCELL int][off: 2*NCELL int][grid_pts: 8N][grid_id: 2N]
    const size_t o_fpk  = (size_t)256 * T;
    const size_t o_red  = (size_t)768 * T;
    const size_t o_keys = o_red + (size_t)26 * L;
    const size_t o_cnt  = o_keys + (size_t)4 * L;
    const size_t o_off  = o_cnt + (size_t)2 * NCELL;
    const size_t o_gpts = o_off + (size_t)2 * NCELL;
    const size_t o_gid  = o_gpts + (size_t)8 * N;

    float4* pkps = (float4*)ws;
    int4*   fpk  = (int4*)(ws + o_fpk);
    float*  red  = ws + o_red;
    unsigned long long* keys = (unsigned long long*)(ws + o_keys);
    int*    cnt  = (int*)(ws + o_cnt);
    int*    off  = (int*)(ws + o_off);
    float4* gpts = (float4*)(ws + o_gpts);
    int*    gid  = (int*)(ws + o_gid);

    const int CT = 40;                       // tiles per chunk
    const int SC = (T + CT - 1) / CT;        // 32 chunks

    // graph-capturable async memsets replace the zero/init kernels
    hipMemsetAsync(cnt, 0, (size_t)2 * NCELL * sizeof(int), stream);
    hipMemsetAsync(red, 0, (size_t)26 * L * sizeof(float), stream);

    const int ptasks = 2 * P + 128 * T + 2 * N;
    pip_pack<<<dim3((ptasks + BLK - 1) / BLK), dim3(BLK), 0, stream>>>(
        g1_pos, g2_pos, s1_v, s1_x, s2_v, s2_x, pkps, fpk, cnt, N, T);

    pip_scan<<<dim3(1), dim3(1024), 0, stream>>>(cnt, off);

    pip_scatter<<<dim3((2 * N + BLK - 1) / BLK), dim3(BLK), 0, stream>>>(
        g1_pos, g2_pos, cnt, gpts, gid, N);

    // fused: nbp partial blocks + L nn blocks (2 waves/block -> 2L nn waves)
    const int qblocks = L / 128;             // 32
    const int nbp = qblocks * SC * 2;        // 2048
    const int nbn = L;                       // 4096 (2 queries per block)
    pip_fused<<<dim3(nbp + nbn), dim3(128), 0, stream>>>(
        locs_l, locs_r, pkps, fpk, off, cnt, gpts, gid,
        red, keys, L, T, CT, P, SC, nbp);

    pip_final<<<dim3((L + BLK - 1) / BLK), dim3(BLK), 0, stream>>>(
        red, keys, g1_x, g2_x, W1, b1, W2, b2, out, L);
}